// Round 11
// baseline (4728.275 us; speedup 1.0000x reference)
//
#include <hip/hip_runtime.h>
#include <stdint.h>

namespace {

constexpr int B_ROWS = 131072;

typedef __attribute__((ext_vector_type(8))) short bf16x8;
typedef __attribute__((ext_vector_type(4))) float f32x4;

__device__ __forceinline__ unsigned short f2bf(float f) {
  unsigned u = __builtin_bit_cast(unsigned, f);
  u += 0x7fffu + ((u >> 16) & 1u);
  return (unsigned short)(u >> 16);
}
__device__ __forceinline__ float bf2f(unsigned short h) {
  unsigned u = ((unsigned)h) << 16;
  return __builtin_bit_cast(float, u);
}
__device__ __forceinline__ float sigm(float v) { return 1.0f / (1.0f + __expf(-v)); }

// ---------- weight packing ----------

__global__ void pack_t_k(const float* __restrict__ W, unsigned short* __restrict__ Wt) {
  int idx = blockIdx.x * 256 + threadIdx.x;  // 512*512
  int n = idx >> 9, k = idx & 511;
  Wt[idx] = f2bf(W[(k << 9) + n]);
}

__global__ void pack_zgr_k(const float* __restrict__ dgmW, unsigned short* __restrict__ Wt) {
  long idx = (long)blockIdx.x * 256 + threadIdx.x;  // 3*1536*1024
  int l = (int)(idx / (1536 * 1024));
  int rest = (int)(idx - (long)l * (1536 * 1024));
  int n = rest >> 10, k = rest & 1023;
  int g = n >> 9, nn = n & 511;
  const int xi0[3] = {0, 3, 6};
  const int xi1[3] = {2, 4, 8};
  const int si[3] = {1, 5, 7};
  float v;
  if (k < 512)
    v = dgmW[(((long)(l * 12 + xi0[g]) << 9) + k) * 512 + nn] +
        dgmW[(((long)(l * 12 + xi1[g]) << 9) + k) * 512 + nn];
  else
    v = dgmW[(((long)(l * 12 + si[g]) << 9) + (k - 512)) * 512 + nn];
  Wt[idx] = f2bf(v);
}

__global__ void pack_h_k(const float* __restrict__ dgmW, unsigned short* __restrict__ Wt) {
  long idx = (long)blockIdx.x * 256 + threadIdx.x;  // 3*512*1024
  int l = (int)(idx / (512 * 1024));
  int rest = (int)(idx - (long)l * (512 * 1024));
  int n = rest >> 10, k = rest & 1023;
  float v;
  if (k < 512)
    v = dgmW[(((long)(l * 12 + 9) << 9) + k) * 512 + n] +
        dgmW[(((long)(l * 12 + 11) << 9) + k) * 512 + n];
  else
    v = dgmW[(((long)(l * 12 + 10) << 9) + (k - 512)) * 512 + n];
  Wt[idx] = f2bf(v);
}

__global__ void pack_bias_k(const float* __restrict__ dgmb, float* __restrict__ bzgr,
                            float* __restrict__ bh) {
  int idx = blockIdx.x * 256 + threadIdx.x;  // 3*2048
  if (idx >= 3 * 2048) return;
  int l = idx >> 11, n = idx & 2047;
  const float* bl = dgmb + l * 12 * 512;
  if (n < 1536) {
    int g = n >> 9, nn = n & 511;
    bzgr[l * 1536 + n] =
        bl[(g * 3 + 0) * 512 + nn] + bl[(g * 3 + 1) * 512 + nn] + bl[(g * 3 + 2) * 512 + nn];
  } else {
    int nn = n - 1536;
    bh[l * 512 + nn] = bl[9 * 512 + nn] + bl[10 * 512 + nn] + bl[11 * 512 + nn];
  }
}

// ---------- front input layer ----------
__global__ void front0_k(const float* __restrict__ X, const float* __restrict__ t,
                         const float* __restrict__ Win, const float* __restrict__ bin,
                         unsigned short* __restrict__ x0, long row0) {
  long idx = (long)blockIdx.x * 256 + threadIdx.x;  // rows*512
  long r = idx >> 9;
  int c = (int)(idx & 511);
  long gr = row0 + r;
  float a = X[gr * 2] * Win[c] + X[gr * 2 + 1] * Win[512 + c] + t[gr] * Win[1024 + c] + bin[c];
  x0[idx] = f2bf(tanhf(a));
}

// ---------- output head ----------
__global__ void head_k(const unsigned short* __restrict__ S, const float* __restrict__ Wout,
                       const float* __restrict__ bout, float* __restrict__ out, long row0) {
  const int lane = threadIdx.x & 63, wid = threadIdx.x >> 6;
  const long r = (long)blockIdx.x * 4 + wid;
  bf16x8 sv = *(const bf16x8*)&S[r * 512 + lane * 8];
  float sum = 0.f;
#pragma unroll
  for (int i = 0; i < 8; ++i) sum += bf2f((unsigned short)sv[i]) * Wout[lane * 8 + i];
#pragma unroll
  for (int off = 32; off > 0; off >>= 1) sum += __shfl_down(sum, off);
  if (lane == 0) out[row0 + r] = sum + bout[0];
}

#define GLD(gsrc, ldst)                                                      \
  __builtin_amdgcn_global_load_lds(                                          \
      (const __attribute__((address_space(1))) void*)(gsrc),                 \
      (__attribute__((address_space(3))) void*)(ldst), 16, 0, 0)

// ---------- occupancy-first 128x128 GEMM (R10 + bigger wave tile) ----------
// R10 confirmed the occupancy lever (19->49%, 518->628 TF). Cycle accounting
// then showed LDS-read ~74% busy (64x32 wave tile = 21 FLOP/LDS-byte) as the
// next wall. This round: 64x64 wave tile (block 128x128, 4 waves 2x2):
// 32 FLOP/LDS-byte (2x), staging bytes/FLOP -25%, acc[4][4]=64 AGPR +
// ~60 VGPR ~ 124 total -- under the 128 halving threshold (m69) so still
// 4 waves/SIMD; LDS 32KB -> reg-limited 4 blocks/CU (~50% occupancy).
// Single-buffered 2-sync loop; cross-block overlap hides stage/drain (m114).
// LDS: A [2 ks][128 rows][32 sh] = 16KB, B same = 16KB.
// Swizzle (proven, 0 conflicts): granule ^= (row>>1)&3 on global source and
// ds_read; LDS dest linear.
template <int EPI, int KT>
__global__ __launch_bounds__(256, 4) void gemmS_k(
    const unsigned short* __restrict__ a0, const unsigned short* __restrict__ a1,
    const unsigned short* __restrict__ wt, const float* __restrict__ bias,
    unsigned short* __restrict__ o0, unsigned short* __restrict__ o1,
    unsigned short* __restrict__ o2, const unsigned short* __restrict__ e0,
    const unsigned short* __restrict__ e1) {
  constexpr int K = KT * 64;
  __shared__ unsigned short lds[16384];
  const int tid = threadIdx.x;
  const int lane = tid & 63, wid = tid >> 6;
  const int wm = wid >> 1, wn = wid & 1;
  const int lr = lane & 15, kk = lane >> 4;

  // bijective XCD swizzle (m204), col-fastest: col-blocks of one A-panel run
  // consecutively on one XCD (A-panel + B stay L2-resident).
  const int gx = gridDim.x;
  const int nwg = gx * (int)gridDim.y;
  const int orig = (int)blockIdx.y * gx + (int)blockIdx.x;
  const int q = nwg >> 3, rr = nwg & 7;
  const int xcd = orig & 7, lo = orig >> 3;
  const int wg = ((xcd < rr) ? xcd * (q + 1) : rr * (q + 1) + (xcd - rr) * q) + lo;
  const long brow = (long)(wg / gx) * 128;
  const int bcol = (wg % gx) * 128;

  const int gp8 = ((kk ^ ((lr >> 1) & 3)) << 3);
  const int a_rd = (wm * 64 + lr) * 32 + gp8;         // + m*512 + ks*4096
  const int b_rd = 8192 + (wn * 64 + lr) * 32 + gp8;  // + n*512 + ks*4096

  f32x4 acc[4][4] = {};

  auto stage = [&](int kt) {
    const unsigned short* src = (KT == 16 && (kt & 8)) ? a1 : a0;
    const int ko = (kt & 7) * 64;
    // A: 1024 16B-units: u -> ks=u>>9, row=(u&511)>>2, granule=(u&3)
#pragma unroll
    for (int i = 0; i < 4; ++i) {
      const int u = tid + (i << 8);
      const int ks = u >> 9, rem = u & 511;
      const int row = rem >> 2;
      const int gl = (rem & 3) ^ ((row >> 1) & 3);
      GLD(src + (brow + row) * 512 + ko + ks * 32 + gl * 8, lds + u * 8);
    }
    // B: 1024 16B-units, same decomposition
#pragma unroll
    for (int i = 0; i < 4; ++i) {
      const int u = tid + (i << 8);
      const int ks = u >> 9, rem = u & 511;
      const int row = rem >> 2;
      const int gl = (rem & 3) ^ ((row >> 1) & 3);
      GLD(wt + (size_t)(bcol + row) * K + kt * 64 + ks * 32 + gl * 8, lds + 8192 + u * 8);
    }
  };

  for (int t = 0; t < KT; ++t) {
    __syncthreads();  // prior tile's reads complete before overwrite
    stage(t);
    __syncthreads();  // compiler-inserted vmcnt(0): staged data visible
#pragma unroll
    for (int ks = 0; ks < 2; ++ks) {
      bf16x8 af[4], bf[4];
#pragma unroll
      for (int n = 0; n < 4; ++n)
        bf[n] = *(const bf16x8*)(lds + b_rd + ks * 4096 + n * 512);
#pragma unroll
      for (int m = 0; m < 4; ++m)
        af[m] = *(const bf16x8*)(lds + a_rd + ks * 4096 + m * 512);
      __builtin_amdgcn_s_setprio(1);
#pragma unroll
      for (int m = 0; m < 4; ++m)
#pragma unroll
        for (int n = 0; n < 4; ++n)
          acc[m][n] = __builtin_amdgcn_mfma_f32_16x16x32_bf16(af[m], bf[n], acc[m][n], 0, 0, 0);
      __builtin_amdgcn_s_setprio(0);
    }
  }

  // epilogue
#pragma unroll
  for (int m = 0; m < 4; ++m) {
#pragma unroll
    for (int n = 0; n < 4; ++n) {
      const int col = bcol + wn * 64 + n * 16 + lr;
      const float bs = bias[col];
#pragma unroll
      for (int j = 0; j < 4; ++j) {
        const long row = brow + wm * 64 + m * 16 + kk * 4 + j;
        float v = acc[m][n][j] + bs;
        if constexpr (EPI == 0) {
          o0[row * 512 + col] = f2bf(tanhf(v));
        } else if constexpr (EPI == 1) {
          unsigned short b = f2bf(v);
          o0[row * 512 + col] = b;
          o1[row * 512 + col] = b;
        } else if constexpr (EPI == 2) {
          const int g = col >> 9;
          const int nn = col & 511;
          const float sgv = sigm(v);
          if (g == 0) {
            o0[row * 512 + nn] = f2bf(sgv * bf2f(e0[row * 512 + nn]));  // Z*S
          } else if (g == 1) {
            o1[row * 512 + nn] = f2bf(1.0f - sgv);  // 1-G
          } else {
            o2[row * 512 + nn] = f2bf(sgv * bf2f(e0[row * 512 + nn]));  // S*R
          }
        } else {
          const float h = tanhf(v);
          const float omg = bf2f(e0[row * 512 + col]);
          const float zs = bf2f(e1[row * 512 + col]);
          o0[row * 512 + col] = f2bf(omg * h + zs);  // S_new
        }
      }
    }
  }
}

}  // namespace

extern "C" void kernel_launch(void* const* d_in, const int* in_sizes, int n_in,
                              void* d_out, int out_size, void* d_ws, size_t ws_size,
                              hipStream_t stream) {
  const float* X = (const float*)d_in[0];
  const float* t = (const float*)d_in[1];
  const float* W_in = (const float*)d_in[2];
  const float* b_in = (const float*)d_in[3];
  const float* W_h1 = (const float*)d_in[4];
  const float* b_h1 = (const float*)d_in[5];
  const float* W_hd = (const float*)d_in[6];
  const float* b_hd = (const float*)d_in[7];
  const float* dgm_W = (const float*)d_in[8];
  const float* dgm_b = (const float*)d_in[9];
  const float* W_out = (const float*)d_in[10];
  const float* b_out = (const float*)d_in[11];
  float* out = (float*)d_out;
  char* ws = (char*)d_ws;

  size_t off = 0;
  auto alloc = [&](size_t bytes) {
    size_t o = off;
    off = (off + bytes + 255) & ~(size_t)255;
    return o;
  };
  size_t o_wth1 = alloc((size_t)512 * 512 * 2);
  size_t o_wthd = alloc((size_t)512 * 512 * 2);
  size_t o_wtzgr = alloc((size_t)3 * 1536 * 1024 * 2);
  size_t o_wth = alloc((size_t)3 * 512 * 1024 * 2);
  size_t o_bzgr = alloc((size_t)3 * 1536 * 4);
  size_t o_bh = alloc((size_t)3 * 512 * 4);
  size_t actoff = off;

  unsigned short* wth1 = (unsigned short*)(ws + o_wth1);
  unsigned short* wthd = (unsigned short*)(ws + o_wthd);
  unsigned short* wtzgr = (unsigned short*)(ws + o_wtzgr);
  unsigned short* wth = (unsigned short*)(ws + o_wth);
  float* bzgr = (float*)(ws + o_bzgr);
  float* bh = (float*)(ws + o_bh);

  size_t avail = ws_size > actoff ? ws_size - actoff : 0;
  int nch = 1;
  while (nch < 256 && (size_t)(B_ROWS / nch) * 512 * 2 * 5 > avail) nch <<= 1;
  const int R = B_ROWS / nch;
  unsigned short* xb = (unsigned short*)(ws + actoff);
  unsigned short* Sb = xb + (size_t)R * 512;
  unsigned short* ZSb = Sb + (size_t)R * 512;
  unsigned short* OGb = ZSb + (size_t)R * 512;
  unsigned short* SRb = OGb + (size_t)R * 512;

  pack_t_k<<<1024, 256, 0, stream>>>(W_h1, wth1);
  pack_t_k<<<1024, 256, 0, stream>>>(W_hd, wthd);
  pack_zgr_k<<<18432, 256, 0, stream>>>(dgm_W, wtzgr);
  pack_h_k<<<6144, 256, 0, stream>>>(dgm_W, wth);
  pack_bias_k<<<24, 256, 0, stream>>>(dgm_b, bzgr, bh);

  const int MT = R / 128;
  for (int c = 0; c < nch; ++c) {
    long row0 = (long)c * R;
    dim3 g4(4, MT), g12(12, MT);
    // x0 = tanh(inp@W_in + b_in)  -> ZSb (scratch)
    front0_k<<<R * 2, 256, 0, stream>>>(X, t, W_in, b_in, ZSb, row0);
    // x1 = tanh(x0@W_h1 + b_h1)   -> OGb (scratch)
    gemmS_k<0, 8><<<g4, 256, 0, stream>>>(ZSb, ZSb, wth1, b_h1, OGb, nullptr, nullptr,
                                          nullptr, nullptr);
    // x = x1@W_hd + b_hd          -> xb and Sb
    gemmS_k<1, 8><<<g4, 256, 0, stream>>>(OGb, OGb, wthd, b_hd, xb, Sb, nullptr,
                                          nullptr, nullptr);
    for (int l = 0; l < 3; ++l) {
      // gates: [x|S] @ Wzgr -> Z*S, 1-G, S*R
      gemmS_k<2, 16><<<g12, 256, 0, stream>>>(xb, Sb, wtzgr + (size_t)l * 1536 * 1024,
                                              bzgr + l * 1536, ZSb, OGb, SRb, Sb, nullptr);
      // H + S update: [x|S*R] @ Wh ; S = (1-G)*tanh + Z*S
      gemmS_k<3, 16><<<g4, 256, 0, stream>>>(xb, SRb, wth + (size_t)l * 512 * 1024,
                                             bh + l * 512, Sb, nullptr, nullptr, OGb, ZSb);
    }
    head_k<<<R / 4, 256, 0, stream>>>(Sb, W_out, b_out, out, row0);
  }
}

// Round 12
// 3513.243 us; speedup vs baseline: 1.3458x; 1.3458x over previous
//
#include <hip/hip_runtime.h>
#include <stdint.h>

namespace {

constexpr int B_ROWS = 131072;

typedef __attribute__((ext_vector_type(8))) short bf16x8;
typedef __attribute__((ext_vector_type(4))) float f32x4;

__device__ __forceinline__ unsigned short f2bf(float f) {
  unsigned u = __builtin_bit_cast(unsigned, f);
  u += 0x7fffu + ((u >> 16) & 1u);
  return (unsigned short)(u >> 16);
}
__device__ __forceinline__ float bf2f(unsigned short h) {
  unsigned u = ((unsigned)h) << 16;
  return __builtin_bit_cast(float, u);
}
__device__ __forceinline__ float sigm(float v) { return 1.0f / (1.0f + __expf(-v)); }

// ---------- weight packing ----------

__global__ void pack_t_k(const float* __restrict__ W, unsigned short* __restrict__ Wt) {
  int idx = blockIdx.x * 256 + threadIdx.x;  // 512*512
  int n = idx >> 9, k = idx & 511;
  Wt[idx] = f2bf(W[(k << 9) + n]);
}

__global__ void pack_zgr_k(const float* __restrict__ dgmW, unsigned short* __restrict__ Wt) {
  long idx = (long)blockIdx.x * 256 + threadIdx.x;  // 3*1536*1024
  int l = (int)(idx / (1536 * 1024));
  int rest = (int)(idx - (long)l * (1536 * 1024));
  int n = rest >> 10, k = rest & 1023;
  int g = n >> 9, nn = n & 511;
  const int xi0[3] = {0, 3, 6};
  const int xi1[3] = {2, 4, 8};
  const int si[3] = {1, 5, 7};
  float v;
  if (k < 512)
    v = dgmW[(((long)(l * 12 + xi0[g]) << 9) + k) * 512 + nn] +
        dgmW[(((long)(l * 12 + xi1[g]) << 9) + k) * 512 + nn];
  else
    v = dgmW[(((long)(l * 12 + si[g]) << 9) + (k - 512)) * 512 + nn];
  Wt[idx] = f2bf(v);
}

__global__ void pack_h_k(const float* __restrict__ dgmW, unsigned short* __restrict__ Wt) {
  long idx = (long)blockIdx.x * 256 + threadIdx.x;  // 3*512*1024
  int l = (int)(idx / (512 * 1024));
  int rest = (int)(idx - (long)l * (512 * 1024));
  int n = rest >> 10, k = rest & 1023;
  float v;
  if (k < 512)
    v = dgmW[(((long)(l * 12 + 9) << 9) + k) * 512 + n] +
        dgmW[(((long)(l * 12 + 11) << 9) + k) * 512 + n];
  else
    v = dgmW[(((long)(l * 12 + 10) << 9) + (k - 512)) * 512 + n];
  Wt[idx] = f2bf(v);
}

__global__ void pack_bias_k(const float* __restrict__ dgmb, float* __restrict__ bzgr,
                            float* __restrict__ bh) {
  int idx = blockIdx.x * 256 + threadIdx.x;  // 3*2048
  if (idx >= 3 * 2048) return;
  int l = idx >> 11, n = idx & 2047;
  const float* bl = dgmb + l * 12 * 512;
  if (n < 1536) {
    int g = n >> 9, nn = n & 511;
    bzgr[l * 1536 + n] =
        bl[(g * 3 + 0) * 512 + nn] + bl[(g * 3 + 1) * 512 + nn] + bl[(g * 3 + 2) * 512 + nn];
  } else {
    int nn = n - 1536;
    bh[l * 512 + nn] = bl[9 * 512 + nn] + bl[10 * 512 + nn] + bl[11 * 512 + nn];
  }
}

// ---------- front input layer ----------
__global__ void front0_k(const float* __restrict__ X, const float* __restrict__ t,
                         const float* __restrict__ Win, const float* __restrict__ bin,
                         unsigned short* __restrict__ x0, long row0) {
  long idx = (long)blockIdx.x * 256 + threadIdx.x;  // rows*512
  long r = idx >> 9;
  int c = (int)(idx & 511);
  long gr = row0 + r;
  float a = X[gr * 2] * Win[c] + X[gr * 2 + 1] * Win[512 + c] + t[gr] * Win[1024 + c] + bin[c];
  x0[idx] = f2bf(tanhf(a));
}

// ---------- output head ----------
__global__ void head_k(const unsigned short* __restrict__ S, const float* __restrict__ Wout,
                       const float* __restrict__ bout, float* __restrict__ out, long row0) {
  const int lane = threadIdx.x & 63, wid = threadIdx.x >> 6;
  const long r = (long)blockIdx.x * 4 + wid;
  bf16x8 sv = *(const bf16x8*)&S[r * 512 + lane * 8];
  float sum = 0.f;
#pragma unroll
  for (int i = 0; i < 8; ++i) sum += bf2f((unsigned short)sv[i]) * Wout[lane * 8 + i];
#pragma unroll
  for (int off = 32; off > 0; off >>= 1) sum += __shfl_down(sum, off);
  if (lane == 0) out[row0 + r] = sum + bout[0];
}

#define GLD(gsrc, ldst)                                                      \
  __builtin_amdgcn_global_load_lds(                                          \
      (const __attribute__((address_space(1))) void*)(gsrc),                 \
      (__attribute__((address_space(3))) void*)(ldst), 16, 0, 0)

// ---------- 128x64 GEMM, BK=32 double-buffered (R10 occupancy + latency hiding) ----------
// R11 post-mortem: bigger tile lost occupancy + thrashed L2; R10's only
// structural defect is the serially-exposed stage (sync;stage;sync;compute).
// Fix at constant LDS: BK=32 x 2 buffers = 24KB (same as R10's single buf ->
// same blocks/CU), loop = { stage(t+1 -> other buf); compute(t); sync }.
// Staging latency now overlaps this block's own compute AND other blocks'.
// Sync count unchanged. acc[4][2]=32 AGPR + ~50 VGPR -> launch_bounds(256,6)
// targets 6 waves/SIMD (~75% occ cap; LDS cap 6 blocks/CU).
// KT = number of 32-wide K-steps (16 for K=512, 32 for K=1024).
// Swizzle (proven, 0 conflicts): granule ^= (row>>1)&3 on global source and
// ds_read; LDS dest linear.
template <int EPI, int KT>
__global__ __launch_bounds__(256, 6) void gemmS_k(
    const unsigned short* __restrict__ a0, const unsigned short* __restrict__ a1,
    const unsigned short* __restrict__ wt, const float* __restrict__ bias,
    unsigned short* __restrict__ o0, unsigned short* __restrict__ o1,
    unsigned short* __restrict__ o2, const unsigned short* __restrict__ e0,
    const unsigned short* __restrict__ e1) {
  constexpr int K = KT * 32;
  __shared__ unsigned short lds[12288];  // 2 x (A 4096 + B 2048) shorts
  const int tid = threadIdx.x;
  const int lane = tid & 63, wid = tid >> 6;
  const int wm = wid >> 1, wn = wid & 1;
  const int lr = lane & 15, kk = lane >> 4;

  // bijective XCD swizzle (m204), col-fastest: col-blocks of one A-panel run
  // consecutively on one XCD (A-panel + B stay L2-resident).
  const int gx = gridDim.x;
  const int nwg = gx * (int)gridDim.y;
  const int orig = (int)blockIdx.y * gx + (int)blockIdx.x;
  const int q = nwg >> 3, rr = nwg & 7;
  const int xcd = orig & 7, lo = orig >> 3;
  const int wg = ((xcd < rr) ? xcd * (q + 1) : rr * (q + 1) + (xcd - rr) * q) + lo;
  const long brow = (long)(wg / gx) * 128;
  const int bcol = (wg % gx) * 64;

  const int gp8 = ((kk ^ ((lr >> 1) & 3)) << 3);
  const int a_rd = (wm * 64 + lr) * 32 + gp8;         // + m*512
  const int b_rd = 4096 + (wn * 32 + lr) * 32 + gp8;  // + n*512

  f32x4 acc[4][2] = {};

  // stage one BK=32 tile into buffer at dbo (shorts): A 2 loads + B 1 load
  auto stage = [&](int kt, int dbo) {
    const unsigned short* src = (KT == 32 && (kt & 16)) ? a1 : a0;
    const int ko = (kt & 15) * 32;
#pragma unroll
    for (int i = 0; i < 2; ++i) {
      const int u = tid + (i << 8);
      const int row = u >> 2;
      const int gl = (u & 3) ^ ((row >> 1) & 3);
      GLD(src + (brow + row) * 512 + ko + gl * 8, lds + dbo + u * 8);
    }
    {
      const int u = tid;
      const int row = u >> 2;
      const int gl = (u & 3) ^ ((row >> 1) & 3);
      GLD(wt + (size_t)(bcol + row) * K + kt * 32 + gl * 8, lds + dbo + 4096 + u * 8);
    }
  };

  stage(0, 0);
  __syncthreads();  // tile 0 visible

  for (int t = 0; t < KT; ++t) {
    const int dbo = (t & 1) * 6144;
    if (t + 1 < KT) stage(t + 1, dbo ^ 6144);  // overwrites buf of t-1: safe (read-done at t-1's sync)
    bf16x8 af[4];
    bf16x8 bf0 = *(const bf16x8*)(lds + dbo + b_rd);
    bf16x8 bf1 = *(const bf16x8*)(lds + dbo + b_rd + 512);
#pragma unroll
    for (int m = 0; m < 4; ++m) af[m] = *(const bf16x8*)(lds + dbo + a_rd + m * 512);
    __builtin_amdgcn_s_setprio(1);
#pragma unroll
    for (int m = 0; m < 4; ++m) {
      acc[m][0] = __builtin_amdgcn_mfma_f32_16x16x32_bf16(af[m], bf0, acc[m][0], 0, 0, 0);
      acc[m][1] = __builtin_amdgcn_mfma_f32_16x16x32_bf16(af[m], bf1, acc[m][1], 0, 0, 0);
    }
    __builtin_amdgcn_s_setprio(0);
    __syncthreads();  // implicit vmcnt(0): tile t+1 landed; lgkm done
  }

  // epilogue
#pragma unroll
  for (int m = 0; m < 4; ++m) {
#pragma unroll
    for (int n = 0; n < 2; ++n) {
      const int col = bcol + wn * 32 + n * 16 + lr;
      const float bs = bias[col];
#pragma unroll
      for (int j = 0; j < 4; ++j) {
        const long row = brow + wm * 64 + m * 16 + kk * 4 + j;
        float v = acc[m][n][j] + bs;
        if constexpr (EPI == 0) {
          o0[row * 512 + col] = f2bf(tanhf(v));
        } else if constexpr (EPI == 1) {
          unsigned short b = f2bf(v);
          o0[row * 512 + col] = b;
          o1[row * 512 + col] = b;
        } else if constexpr (EPI == 2) {
          const int g = col >> 9;
          const int nn = col & 511;
          const float sgv = sigm(v);
          if (g == 0) {
            o0[row * 512 + nn] = f2bf(sgv * bf2f(e0[row * 512 + nn]));  // Z*S
          } else if (g == 1) {
            o1[row * 512 + nn] = f2bf(1.0f - sgv);  // 1-G
          } else {
            o2[row * 512 + nn] = f2bf(sgv * bf2f(e0[row * 512 + nn]));  // S*R
          }
        } else {
          const float h = tanhf(v);
          const float omg = bf2f(e0[row * 512 + col]);
          const float zs = bf2f(e1[row * 512 + col]);
          o0[row * 512 + col] = f2bf(omg * h + zs);  // S_new
        }
      }
    }
  }
}

}  // namespace

extern "C" void kernel_launch(void* const* d_in, const int* in_sizes, int n_in,
                              void* d_out, int out_size, void* d_ws, size_t ws_size,
                              hipStream_t stream) {
  const float* X = (const float*)d_in[0];
  const float* t = (const float*)d_in[1];
  const float* W_in = (const float*)d_in[2];
  const float* b_in = (const float*)d_in[3];
  const float* W_h1 = (const float*)d_in[4];
  const float* b_h1 = (const float*)d_in[5];
  const float* W_hd = (const float*)d_in[6];
  const float* b_hd = (const float*)d_in[7];
  const float* dgm_W = (const float*)d_in[8];
  const float* dgm_b = (const float*)d_in[9];
  const float* W_out = (const float*)d_in[10];
  const float* b_out = (const float*)d_in[11];
  float* out = (float*)d_out;
  char* ws = (char*)d_ws;

  size_t off = 0;
  auto alloc = [&](size_t bytes) {
    size_t o = off;
    off = (off + bytes + 255) & ~(size_t)255;
    return o;
  };
  size_t o_wth1 = alloc((size_t)512 * 512 * 2);
  size_t o_wthd = alloc((size_t)512 * 512 * 2);
  size_t o_wtzgr = alloc((size_t)3 * 1536 * 1024 * 2);
  size_t o_wth = alloc((size_t)3 * 512 * 1024 * 2);
  size_t o_bzgr = alloc((size_t)3 * 1536 * 4);
  size_t o_bh = alloc((size_t)3 * 512 * 4);
  size_t actoff = off;

  unsigned short* wth1 = (unsigned short*)(ws + o_wth1);
  unsigned short* wthd = (unsigned short*)(ws + o_wthd);
  unsigned short* wtzgr = (unsigned short*)(ws + o_wtzgr);
  unsigned short* wth = (unsigned short*)(ws + o_wth);
  float* bzgr = (float*)(ws + o_bzgr);
  float* bh = (float*)(ws + o_bh);

  size_t avail = ws_size > actoff ? ws_size - actoff : 0;
  int nch = 1;
  while (nch < 256 && (size_t)(B_ROWS / nch) * 512 * 2 * 5 > avail) nch <<= 1;
  const int R = B_ROWS / nch;
  unsigned short* xb = (unsigned short*)(ws + actoff);
  unsigned short* Sb = xb + (size_t)R * 512;
  unsigned short* ZSb = Sb + (size_t)R * 512;
  unsigned short* OGb = ZSb + (size_t)R * 512;
  unsigned short* SRb = OGb + (size_t)R * 512;

  pack_t_k<<<1024, 256, 0, stream>>>(W_h1, wth1);
  pack_t_k<<<1024, 256, 0, stream>>>(W_hd, wthd);
  pack_zgr_k<<<18432, 256, 0, stream>>>(dgm_W, wtzgr);
  pack_h_k<<<6144, 256, 0, stream>>>(dgm_W, wth);
  pack_bias_k<<<24, 256, 0, stream>>>(dgm_b, bzgr, bh);

  const int MT = R / 128;
  for (int c = 0; c < nch; ++c) {
    long row0 = (long)c * R;
    dim3 g8(8, MT), g24(24, MT);
    // x0 = tanh(inp@W_in + b_in)  -> ZSb (scratch)
    front0_k<<<R * 2, 256, 0, stream>>>(X, t, W_in, b_in, ZSb, row0);
    // x1 = tanh(x0@W_h1 + b_h1)   -> OGb (scratch)
    gemmS_k<0, 16><<<g8, 256, 0, stream>>>(ZSb, ZSb, wth1, b_h1, OGb, nullptr, nullptr,
                                           nullptr, nullptr);
    // x = x1@W_hd + b_hd          -> xb and Sb
    gemmS_k<1, 16><<<g8, 256, 0, stream>>>(OGb, OGb, wthd, b_hd, xb, Sb, nullptr,
                                           nullptr, nullptr);
    for (int l = 0; l < 3; ++l) {
      // gates: [x|S] @ Wzgr -> Z*S, 1-G, S*R
      gemmS_k<2, 32><<<g24, 256, 0, stream>>>(xb, Sb, wtzgr + (size_t)l * 1536 * 1024,
                                              bzgr + l * 1536, ZSb, OGb, SRb, Sb, nullptr);
      // H + S update: [x|S*R] @ Wh ; S = (1-G)*tanh + Z*S
      gemmS_k<3, 32><<<g8, 256, 0, stream>>>(xb, SRb, wth + (size_t)l * 512 * 1024,
                                             bh + l * 512, Sb, nullptr, nullptr, OGb, ZSb);
    }
    head_k<<<R / 4, 256, 0, stream>>>(Sb, W_out, b_out, out, row0);
  }
}

// Round 13
// 3255.868 us; speedup vs baseline: 1.4522x; 1.0790x over previous
//
#include <hip/hip_runtime.h>
#include <stdint.h>

namespace {

constexpr int B_ROWS = 131072;

typedef __attribute__((ext_vector_type(8))) short bf16x8;
typedef __attribute__((ext_vector_type(4))) float f32x4;

__device__ __forceinline__ unsigned short f2bf(float f) {
  unsigned u = __builtin_bit_cast(unsigned, f);
  u += 0x7fffu + ((u >> 16) & 1u);
  return (unsigned short)(u >> 16);
}
__device__ __forceinline__ float bf2f(unsigned short h) {
  unsigned u = ((unsigned)h) << 16;
  return __builtin_bit_cast(float, u);
}
__device__ __forceinline__ float sigm(float v) { return 1.0f / (1.0f + __expf(-v)); }

// ---------- weight packing ----------

__global__ void pack_t_k(const float* __restrict__ W, unsigned short* __restrict__ Wt) {
  int idx = blockIdx.x * 256 + threadIdx.x;  // 512*512
  int n = idx >> 9, k = idx & 511;
  Wt[idx] = f2bf(W[(k << 9) + n]);
}

__global__ void pack_zgr_k(const float* __restrict__ dgmW, unsigned short* __restrict__ Wt) {
  long idx = (long)blockIdx.x * 256 + threadIdx.x;  // 3*1536*1024
  int l = (int)(idx / (1536 * 1024));
  int rest = (int)(idx - (long)l * (1536 * 1024));
  int n = rest >> 10, k = rest & 1023;
  int g = n >> 9, nn = n & 511;
  const int xi0[3] = {0, 3, 6};
  const int xi1[3] = {2, 4, 8};
  const int si[3] = {1, 5, 7};
  float v;
  if (k < 512)
    v = dgmW[(((long)(l * 12 + xi0[g]) << 9) + k) * 512 + nn] +
        dgmW[(((long)(l * 12 + xi1[g]) << 9) + k) * 512 + nn];
  else
    v = dgmW[(((long)(l * 12 + si[g]) << 9) + (k - 512)) * 512 + nn];
  Wt[idx] = f2bf(v);
}

__global__ void pack_h_k(const float* __restrict__ dgmW, unsigned short* __restrict__ Wt) {
  long idx = (long)blockIdx.x * 256 + threadIdx.x;  // 3*512*1024
  int l = (int)(idx / (512 * 1024));
  int rest = (int)(idx - (long)l * (512 * 1024));
  int n = rest >> 10, k = rest & 1023;
  float v;
  if (k < 512)
    v = dgmW[(((long)(l * 12 + 9) << 9) + k) * 512 + n] +
        dgmW[(((long)(l * 12 + 11) << 9) + k) * 512 + n];
  else
    v = dgmW[(((long)(l * 12 + 10) << 9) + (k - 512)) * 512 + n];
  Wt[idx] = f2bf(v);
}

__global__ void pack_bias_k(const float* __restrict__ dgmb, float* __restrict__ bzgr,
                            float* __restrict__ bh) {
  int idx = blockIdx.x * 256 + threadIdx.x;  // 3*2048
  if (idx >= 3 * 2048) return;
  int l = idx >> 11, n = idx & 2047;
  const float* bl = dgmb + l * 12 * 512;
  if (n < 1536) {
    int g = n >> 9, nn = n & 511;
    bzgr[l * 1536 + n] =
        bl[(g * 3 + 0) * 512 + nn] + bl[(g * 3 + 1) * 512 + nn] + bl[(g * 3 + 2) * 512 + nn];
  } else {
    int nn = n - 1536;
    bh[l * 512 + nn] = bl[9 * 512 + nn] + bl[10 * 512 + nn] + bl[11 * 512 + nn];
  }
}

// ---------- front input layer ----------
__global__ void front0_k(const float* __restrict__ X, const float* __restrict__ t,
                         const float* __restrict__ Win, const float* __restrict__ bin,
                         unsigned short* __restrict__ x0, long row0) {
  long idx = (long)blockIdx.x * 256 + threadIdx.x;  // rows*512
  long r = idx >> 9;
  int c = (int)(idx & 511);
  long gr = row0 + r;
  float a = X[gr * 2] * Win[c] + X[gr * 2 + 1] * Win[512 + c] + t[gr] * Win[1024 + c] + bin[c];
  x0[idx] = f2bf(tanhf(a));
}

// ---------- output head ----------
__global__ void head_k(const unsigned short* __restrict__ S, const float* __restrict__ Wout,
                       const float* __restrict__ bout, float* __restrict__ out, long row0) {
  const int lane = threadIdx.x & 63, wid = threadIdx.x >> 6;
  const long r = (long)blockIdx.x * 4 + wid;
  bf16x8 sv = *(const bf16x8*)&S[r * 512 + lane * 8];
  float sum = 0.f;
#pragma unroll
  for (int i = 0; i < 8; ++i) sum += bf2f((unsigned short)sv[i]) * Wout[lane * 8 + i];
#pragma unroll
  for (int off = 32; off > 0; off >>= 1) sum += __shfl_down(sum, off);
  if (lane == 0) out[row0 + r] = sum + bout[0];
}

#define GLD(gsrc, ldst)                                                      \
  __builtin_amdgcn_global_load_lds(                                          \
      (const __attribute__((address_space(1))) void*)(gsrc),                 \
      (__attribute__((address_space(3))) void*)(ldst), 16, 0, 0)

// ---------- 128x64 GEMM, BK=64 double-buffered, no setprio ----------
// R12 post-mortem: per-CU behavior fits a serial per-tile chain =
// exposed-stage-latency + max(LDS-burst, MFMA) + barrier. R10 (single-buf
// BK=64): ~450cy exposed latency + 576cy LDS = 1031cy/tile (matches).
// R12 (dbuf BK=32): compute 288cy < load latency -> latency still exposed,
// 2x tiles -> net loss. Fix: BK=64 dbuf -- compute (576cy) > load latency,
// stage fully hidden, chain ~ max(576,310)+barrier ~ 700cy, same tile count
// as R10. LDS 2x24KB=48KB -> 3 blocks/CU; regs ~72/wave.
// Also dropped s_setprio: T5 needs phase role-split (absent here); m190
// measured it negative on lockstep GEMM, and at multi-block it starves
// co-resident blocks' loads during MFMA bursts.
// KT = K/64 (8 for K=512, 16 for K=1024; a1 used for kt>=8 when KT==16).
// Swizzle (proven, 0 conflicts): granule ^= (row>>1)&3 on global source and
// ds_read; LDS dest linear.
template <int EPI, int KT>
__global__ __launch_bounds__(256, 4) void gemmS_k(
    const unsigned short* __restrict__ a0, const unsigned short* __restrict__ a1,
    const unsigned short* __restrict__ wt, const float* __restrict__ bias,
    unsigned short* __restrict__ o0, unsigned short* __restrict__ o1,
    unsigned short* __restrict__ o2, const unsigned short* __restrict__ e0,
    const unsigned short* __restrict__ e1) {
  constexpr int K = KT * 64;
  __shared__ unsigned short lds[24576];  // 2 x (A 8192 + B 4096) shorts = 48KB
  const int tid = threadIdx.x;
  const int lane = tid & 63, wid = tid >> 6;
  const int wm = wid >> 1, wn = wid & 1;
  const int lr = lane & 15, kk = lane >> 4;

  // bijective XCD swizzle (m204), col-fastest: col-blocks of one A-panel run
  // consecutively on one XCD (A-panel + B stay L2-resident).
  const int gx = gridDim.x;
  const int nwg = gx * (int)gridDim.y;
  const int orig = (int)blockIdx.y * gx + (int)blockIdx.x;
  const int q = nwg >> 3, rr = nwg & 7;
  const int xcd = orig & 7, lo = orig >> 3;
  const int wg = ((xcd < rr) ? xcd * (q + 1) : rr * (q + 1) + (xcd - rr) * q) + lo;
  const long brow = (long)(wg / gx) * 128;
  const int bcol = (wg % gx) * 64;

  const int gp8 = ((kk ^ ((lr >> 1) & 3)) << 3);
  const int a_rd = (wm * 64 + lr) * 32 + gp8;         // + m*512 + ks*4096 + buf
  const int b_rd = 8192 + (wn * 32 + lr) * 32 + gp8;  // + n*512 + ks*2048 + buf

  f32x4 acc[4][2] = {};

  // stage one BK=64 tile into buffer at dbo (shorts): A 4 loads + B 2 loads
  auto stage = [&](int kt, int dbo) {
    const unsigned short* src = (KT == 16 && (kt & 8)) ? a1 : a0;
    const int ko = (kt & 7) * 64;
    // A: 1024 16B-units: u -> ks=u>>9, row=(u&511)>>2, granule=(u&3)
#pragma unroll
    for (int i = 0; i < 4; ++i) {
      const int u = tid + (i << 8);
      const int ks = u >> 9, rem = u & 511;
      const int row = rem >> 2;
      const int gl = (rem & 3) ^ ((row >> 1) & 3);
      GLD(src + (brow + row) * 512 + ko + ks * 32 + gl * 8, lds + dbo + u * 8);
    }
    // B: 512 16B-units: u -> ks=u>>8, row=(u&255)>>2
#pragma unroll
    for (int i = 0; i < 2; ++i) {
      const int u = tid + (i << 8);
      const int ks = u >> 8, rem = u & 255;
      const int row = rem >> 2;
      const int gl = (rem & 3) ^ ((row >> 1) & 3);
      GLD(wt + (size_t)(bcol + row) * K + kt * 64 + ks * 32 + gl * 8,
          lds + dbo + 8192 + u * 8);
    }
  };

  stage(0, 0);
  __syncthreads();  // tile 0 visible (implicit vmcnt(0))

  for (int t = 0; t < KT; ++t) {
    const int dbo = (t & 1) * 12288;
    // stage t+1 into the other buffer: overwrites t-1's buffer, whose reads
    // completed before the sync at the end of tile t-1 (all waves).
    if (t + 1 < KT) stage(t + 1, dbo ^ 12288);
#pragma unroll
    for (int ks = 0; ks < 2; ++ks) {
      bf16x8 af[4];
      bf16x8 bf0 = *(const bf16x8*)(lds + dbo + b_rd + ks * 2048);
      bf16x8 bf1 = *(const bf16x8*)(lds + dbo + b_rd + ks * 2048 + 512);
#pragma unroll
      for (int m = 0; m < 4; ++m)
        af[m] = *(const bf16x8*)(lds + dbo + a_rd + ks * 4096 + m * 512);
#pragma unroll
      for (int m = 0; m < 4; ++m) {
        acc[m][0] = __builtin_amdgcn_mfma_f32_16x16x32_bf16(af[m], bf0, acc[m][0], 0, 0, 0);
        acc[m][1] = __builtin_amdgcn_mfma_f32_16x16x32_bf16(af[m], bf1, acc[m][1], 0, 0, 0);
      }
    }
    __syncthreads();  // implicit vmcnt(0): tile t+1 landed; t's reads done
  }

  // epilogue
#pragma unroll
  for (int m = 0; m < 4; ++m) {
#pragma unroll
    for (int n = 0; n < 2; ++n) {
      const int col = bcol + wn * 32 + n * 16 + lr;
      const float bs = bias[col];
#pragma unroll
      for (int j = 0; j < 4; ++j) {
        const long row = brow + wm * 64 + m * 16 + kk * 4 + j;
        float v = acc[m][n][j] + bs;
        if constexpr (EPI == 0) {
          o0[row * 512 + col] = f2bf(tanhf(v));
        } else if constexpr (EPI == 1) {
          unsigned short b = f2bf(v);
          o0[row * 512 + col] = b;
          o1[row * 512 + col] = b;
        } else if constexpr (EPI == 2) {
          const int g = col >> 9;
          const int nn = col & 511;
          const float sgv = sigm(v);
          if (g == 0) {
            o0[row * 512 + nn] = f2bf(sgv * bf2f(e0[row * 512 + nn]));  // Z*S
          } else if (g == 1) {
            o1[row * 512 + nn] = f2bf(1.0f - sgv);  // 1-G
          } else {
            o2[row * 512 + nn] = f2bf(sgv * bf2f(e0[row * 512 + nn]));  // S*R
          }
        } else {
          const float h = tanhf(v);
          const float omg = bf2f(e0[row * 512 + col]);
          const float zs = bf2f(e1[row * 512 + col]);
          o0[row * 512 + col] = f2bf(omg * h + zs);  // S_new
        }
      }
    }
  }
}

}  // namespace

extern "C" void kernel_launch(void* const* d_in, const int* in_sizes, int n_in,
                              void* d_out, int out_size, void* d_ws, size_t ws_size,
                              hipStream_t stream) {
  const float* X = (const float*)d_in[0];
  const float* t = (const float*)d_in[1];
  const float* W_in = (const float*)d_in[2];
  const float* b_in = (const float*)d_in[3];
  const float* W_h1 = (const float*)d_in[4];
  const float* b_h1 = (const float*)d_in[5];
  const float* W_hd = (const float*)d_in[6];
  const float* b_hd = (const float*)d_in[7];
  const float* dgm_W = (const float*)d_in[8];
  const float* dgm_b = (const float*)d_in[9];
  const float* W_out = (const float*)d_in[10];
  const float* b_out = (const float*)d_in[11];
  float* out = (float*)d_out;
  char* ws = (char*)d_ws;

  size_t off = 0;
  auto alloc = [&](size_t bytes) {
    size_t o = off;
    off = (off + bytes + 255) & ~(size_t)255;
    return o;
  };
  size_t o_wth1 = alloc((size_t)512 * 512 * 2);
  size_t o_wthd = alloc((size_t)512 * 512 * 2);
  size_t o_wtzgr = alloc((size_t)3 * 1536 * 1024 * 2);
  size_t o_wth = alloc((size_t)3 * 512 * 1024 * 2);
  size_t o_bzgr = alloc((size_t)3 * 1536 * 4);
  size_t o_bh = alloc((size_t)3 * 512 * 4);
  size_t actoff = off;

  unsigned short* wth1 = (unsigned short*)(ws + o_wth1);
  unsigned short* wthd = (unsigned short*)(ws + o_wthd);
  unsigned short* wtzgr = (unsigned short*)(ws + o_wtzgr);
  unsigned short* wth = (unsigned short*)(ws + o_wth);
  float* bzgr = (float*)(ws + o_bzgr);
  float* bh = (float*)(ws + o_bh);

  size_t avail = ws_size > actoff ? ws_size - actoff : 0;
  int nch = 1;
  while (nch < 256 && (size_t)(B_ROWS / nch) * 512 * 2 * 5 > avail) nch <<= 1;
  const int R = B_ROWS / nch;
  unsigned short* xb = (unsigned short*)(ws + actoff);
  unsigned short* Sb = xb + (size_t)R * 512;
  unsigned short* ZSb = Sb + (size_t)R * 512;
  unsigned short* OGb = ZSb + (size_t)R * 512;
  unsigned short* SRb = OGb + (size_t)R * 512;

  pack_t_k<<<1024, 256, 0, stream>>>(W_h1, wth1);
  pack_t_k<<<1024, 256, 0, stream>>>(W_hd, wthd);
  pack_zgr_k<<<18432, 256, 0, stream>>>(dgm_W, wtzgr);
  pack_h_k<<<6144, 256, 0, stream>>>(dgm_W, wth);
  pack_bias_k<<<24, 256, 0, stream>>>(dgm_b, bzgr, bh);

  const int MT = R / 128;
  for (int c = 0; c < nch; ++c) {
    long row0 = (long)c * R;
    dim3 g8(8, MT), g24(24, MT);
    // x0 = tanh(inp@W_in + b_in)  -> ZSb (scratch)
    front0_k<<<R * 2, 256, 0, stream>>>(X, t, W_in, b_in, ZSb, row0);
    // x1 = tanh(x0@W_h1 + b_h1)   -> OGb (scratch)
    gemmS_k<0, 8><<<g8, 256, 0, stream>>>(ZSb, ZSb, wth1, b_h1, OGb, nullptr, nullptr,
                                          nullptr, nullptr);
    // x = x1@W_hd + b_hd          -> xb and Sb
    gemmS_k<1, 8><<<g8, 256, 0, stream>>>(OGb, OGb, wthd, b_hd, xb, Sb, nullptr,
                                          nullptr, nullptr);
    for (int l = 0; l < 3; ++l) {
      // gates: [x|S] @ Wzgr -> Z*S, 1-G, S*R
      gemmS_k<2, 16><<<g24, 256, 0, stream>>>(xb, Sb, wtzgr + (size_t)l * 1536 * 1024,
                                              bzgr + l * 1536, ZSb, OGb, SRb, Sb, nullptr);
      // H + S update: [x|S*R] @ Wh ; S = (1-G)*tanh + Z*S
      gemmS_k<3, 16><<<g8, 256, 0, stream>>>(xb, SRb, wth + (size_t)l * 512 * 1024,
                                             bh + l * 512, Sb, nullptr, nullptr, OGb, ZSb);
    }
    head_k<<<R / 4, 256, 0, stream>>>(Sb, W_out, b_out, out, row0);
  }
}

// Round 14
// 3027.472 us; speedup vs baseline: 1.5618x; 1.0754x over previous
//
#include <hip/hip_runtime.h>
#include <stdint.h>

namespace {

constexpr int B_ROWS = 131072;

typedef __attribute__((ext_vector_type(8))) short bf16x8;
typedef __attribute__((ext_vector_type(4))) float f32x4;

__device__ __forceinline__ unsigned short f2bf(float f) {
  unsigned u = __builtin_bit_cast(unsigned, f);
  u += 0x7fffu + ((u >> 16) & 1u);
  return (unsigned short)(u >> 16);
}
__device__ __forceinline__ float bf2f(unsigned short h) {
  unsigned u = ((unsigned)h) << 16;
  return __builtin_bit_cast(float, u);
}
__device__ __forceinline__ float sigm(float v) { return 1.0f / (1.0f + __expf(-v)); }

// ---------- weight packing ----------

__global__ void pack_t_k(const float* __restrict__ W, unsigned short* __restrict__ Wt) {
  int idx = blockIdx.x * 256 + threadIdx.x;  // 512*512
  int n = idx >> 9, k = idx & 511;
  Wt[idx] = f2bf(W[(k << 9) + n]);
}

__global__ void pack_zgr_k(const float* __restrict__ dgmW, unsigned short* __restrict__ Wt) {
  long idx = (long)blockIdx.x * 256 + threadIdx.x;  // 3*1536*1024
  int l = (int)(idx / (1536 * 1024));
  int rest = (int)(idx - (long)l * (1536 * 1024));
  int n = rest >> 10, k = rest & 1023;
  int g = n >> 9, nn = n & 511;
  const int xi0[3] = {0, 3, 6};
  const int xi1[3] = {2, 4, 8};
  const int si[3] = {1, 5, 7};
  float v;
  if (k < 512)
    v = dgmW[(((long)(l * 12 + xi0[g]) << 9) + k) * 512 + nn] +
        dgmW[(((long)(l * 12 + xi1[g]) << 9) + k) * 512 + nn];
  else
    v = dgmW[(((long)(l * 12 + si[g]) << 9) + (k - 512)) * 512 + nn];
  Wt[idx] = f2bf(v);
}

__global__ void pack_h_k(const float* __restrict__ dgmW, unsigned short* __restrict__ Wt) {
  long idx = (long)blockIdx.x * 256 + threadIdx.x;  // 3*512*1024
  int l = (int)(idx / (512 * 1024));
  int rest = (int)(idx - (long)l * (512 * 1024));
  int n = rest >> 10, k = rest & 1023;
  float v;
  if (k < 512)
    v = dgmW[(((long)(l * 12 + 9) << 9) + k) * 512 + n] +
        dgmW[(((long)(l * 12 + 11) << 9) + k) * 512 + n];
  else
    v = dgmW[(((long)(l * 12 + 10) << 9) + (k - 512)) * 512 + n];
  Wt[idx] = f2bf(v);
}

__global__ void pack_bias_k(const float* __restrict__ dgmb, float* __restrict__ bzgr,
                            float* __restrict__ bh) {
  int idx = blockIdx.x * 256 + threadIdx.x;  // 3*2048
  if (idx >= 3 * 2048) return;
  int l = idx >> 11, n = idx & 2047;
  const float* bl = dgmb + l * 12 * 512;
  if (n < 1536) {
    int g = n >> 9, nn = n & 511;
    bzgr[l * 1536 + n] =
        bl[(g * 3 + 0) * 512 + nn] + bl[(g * 3 + 1) * 512 + nn] + bl[(g * 3 + 2) * 512 + nn];
  } else {
    int nn = n - 1536;
    bh[l * 512 + nn] = bl[9 * 512 + nn] + bl[10 * 512 + nn] + bl[11 * 512 + nn];
  }
}

// ---------- front input layer ----------
__global__ void front0_k(const float* __restrict__ X, const float* __restrict__ t,
                         const float* __restrict__ Win, const float* __restrict__ bin,
                         unsigned short* __restrict__ x0, long row0) {
  long idx = (long)blockIdx.x * 256 + threadIdx.x;  // rows*512
  long r = idx >> 9;
  int c = (int)(idx & 511);
  long gr = row0 + r;
  float a = X[gr * 2] * Win[c] + X[gr * 2 + 1] * Win[512 + c] + t[gr] * Win[1024 + c] + bin[c];
  x0[idx] = f2bf(tanhf(a));
}

// ---------- output head ----------
__global__ void head_k(const unsigned short* __restrict__ S, const float* __restrict__ Wout,
                       const float* __restrict__ bout, float* __restrict__ out, long row0) {
  const int lane = threadIdx.x & 63, wid = threadIdx.x >> 6;
  const long r = (long)blockIdx.x * 4 + wid;
  bf16x8 sv = *(const bf16x8*)&S[r * 512 + lane * 8];
  float sum = 0.f;
#pragma unroll
  for (int i = 0; i < 8; ++i) sum += bf2f((unsigned short)sv[i]) * Wout[lane * 8 + i];
#pragma unroll
  for (int off = 32; off > 0; off >>= 1) sum += __shfl_down(sum, off);
  if (lane == 0) out[row0 + r] = sum + bout[0];
}

#define GLD(gsrc, ldst)                                                      \
  __builtin_amdgcn_global_load_lds(                                          \
      (const __attribute__((address_space(1))) void*)(gsrc),                 \
      (__attribute__((address_space(3))) void*)(ldst), 16, 0, 0)

// ---------- 128x64 GEMM, single-buffer READ-HOIST pipeline ----------
// R13 post-mortem: dbuf variants lose the occupancy they need (48KB -> 3
// blocks/CU); R10 (24KB, 4 blocks, 49% occ, 165us gates = 624 TF ~ m248's
// 655 2-phase reference) remains best but exposes the full ~500cy stage
// latency between its two syncs. This round: classic single-buffer pipeline
// at IDENTICAL LDS/occupancy --
//   reads(t)->regs ; bar ; stage(t+1 -> SAME buffer) ; MFMA(t) ; bar+vmcnt0
// B1 guarantees every wave's LDS reads of tile t retired before any staged
// byte of t+1 lands; B2's implicit vmcnt(0) makes t+1 resident. Stage
// latency now overlaps the MFMA cluster (~310cy) instead of being serial.
// Frag regs +48 VGPR -> ~100 total, same 65-128 occupancy bucket as R10.
// s_setprio dropped (m190: negative on lockstep GEMM).
// KT = K/64 (8 for K=512, 16 for K=1024; a1 used for kt>=8 when KT==16).
// Swizzle (proven, 0 conflicts): granule ^= (row>>1)&3 on global source and
// ds_read; LDS dest linear.
template <int EPI, int KT>
__global__ __launch_bounds__(256, 4) void gemmS_k(
    const unsigned short* __restrict__ a0, const unsigned short* __restrict__ a1,
    const unsigned short* __restrict__ wt, const float* __restrict__ bias,
    unsigned short* __restrict__ o0, unsigned short* __restrict__ o1,
    unsigned short* __restrict__ o2, const unsigned short* __restrict__ e0,
    const unsigned short* __restrict__ e1) {
  constexpr int K = KT * 64;
  __shared__ unsigned short lds[12288];  // A 2ks x 128 x 32 | B 2ks x 64 x 32 = 24KB
  const int tid = threadIdx.x;
  const int lane = tid & 63, wid = tid >> 6;
  const int wm = wid >> 1, wn = wid & 1;
  const int lr = lane & 15, kk = lane >> 4;

  // bijective XCD swizzle (m204), col-fastest: col-blocks of one A-panel run
  // consecutively on one XCD (A-panel + B stay L2-resident).
  const int gx = gridDim.x;
  const int nwg = gx * (int)gridDim.y;
  const int orig = (int)blockIdx.y * gx + (int)blockIdx.x;
  const int q = nwg >> 3, rr = nwg & 7;
  const int xcd = orig & 7, lo = orig >> 3;
  const int wg = ((xcd < rr) ? xcd * (q + 1) : rr * (q + 1) + (xcd - rr) * q) + lo;
  const long brow = (long)(wg / gx) * 128;
  const int bcol = (wg % gx) * 64;

  const int gp8 = ((kk ^ ((lr >> 1) & 3)) << 3);
  const int a_rd = (wm * 64 + lr) * 32 + gp8;         // + m*512 + ks*4096
  const int b_rd = 8192 + (wn * 32 + lr) * 32 + gp8;  // + n*512 + ks*2048

  f32x4 acc[4][2] = {};

  auto stage = [&](int kt) {
    const unsigned short* src = (KT == 16 && (kt & 8)) ? a1 : a0;
    const int ko = (kt & 7) * 64;
    // A: 1024 16B-units: u -> ks=u>>9, row=(u&511)>>2, granule=(u&3)
#pragma unroll
    for (int i = 0; i < 4; ++i) {
      const int u = tid + (i << 8);
      const int ks = u >> 9, rem = u & 511;
      const int row = rem >> 2;
      const int gl = (rem & 3) ^ ((row >> 1) & 3);
      GLD(src + (brow + row) * 512 + ko + ks * 32 + gl * 8, lds + u * 8);
    }
    // B: 512 16B-units: u -> ks=u>>8, row=(u&255)>>2
#pragma unroll
    for (int i = 0; i < 2; ++i) {
      const int u = tid + (i << 8);
      const int ks = u >> 8, rem = u & 255;
      const int row = rem >> 2;
      const int gl = (rem & 3) ^ ((row >> 1) & 3);
      GLD(wt + (size_t)(bcol + row) * K + kt * 64 + ks * 32 + gl * 8, lds + 8192 + u * 8);
    }
  };

  stage(0);
  __syncthreads();  // tile 0 resident (implicit vmcnt(0))

  for (int t = 0; t < KT; ++t) {
    // hoist ALL fragment reads of tile t into registers
    bf16x8 af0[4], af1[4];
    bf16x8 b00 = *(const bf16x8*)(lds + b_rd);
    bf16x8 b01 = *(const bf16x8*)(lds + b_rd + 512);
    bf16x8 b10 = *(const bf16x8*)(lds + b_rd + 2048);
    bf16x8 b11 = *(const bf16x8*)(lds + b_rd + 2048 + 512);
#pragma unroll
    for (int m = 0; m < 4; ++m) af0[m] = *(const bf16x8*)(lds + a_rd + m * 512);
#pragma unroll
    for (int m = 0; m < 4; ++m) af1[m] = *(const bf16x8*)(lds + a_rd + 4096 + m * 512);
    __syncthreads();  // B1: every wave's reads of tile t retired (lgkm drain; no vm pending)
    if (t + 1 < KT) stage(t + 1);  // overwrite the single buffer; lands after B1
    // MFMA consumes registers only; stage latency overlaps this cluster
#pragma unroll
    for (int m = 0; m < 4; ++m) {
      acc[m][0] = __builtin_amdgcn_mfma_f32_16x16x32_bf16(af0[m], b00, acc[m][0], 0, 0, 0);
      acc[m][1] = __builtin_amdgcn_mfma_f32_16x16x32_bf16(af0[m], b01, acc[m][1], 0, 0, 0);
    }
#pragma unroll
    for (int m = 0; m < 4; ++m) {
      acc[m][0] = __builtin_amdgcn_mfma_f32_16x16x32_bf16(af1[m], b10, acc[m][0], 0, 0, 0);
      acc[m][1] = __builtin_amdgcn_mfma_f32_16x16x32_bf16(af1[m], b11, acc[m][1], 0, 0, 0);
    }
    __syncthreads();  // B2: implicit vmcnt(0) -> tile t+1 resident for next reads
  }

  // epilogue
#pragma unroll
  for (int m = 0; m < 4; ++m) {
#pragma unroll
    for (int n = 0; n < 2; ++n) {
      const int col = bcol + wn * 32 + n * 16 + lr;
      const float bs = bias[col];
#pragma unroll
      for (int j = 0; j < 4; ++j) {
        const long row = brow + wm * 64 + m * 16 + kk * 4 + j;
        float v = acc[m][n][j] + bs;
        if constexpr (EPI == 0) {
          o0[row * 512 + col] = f2bf(tanhf(v));
        } else if constexpr (EPI == 1) {
          unsigned short b = f2bf(v);
          o0[row * 512 + col] = b;
          o1[row * 512 + col] = b;
        } else if constexpr (EPI == 2) {
          const int g = col >> 9;
          const int nn = col & 511;
          const float sgv = sigm(v);
          if (g == 0) {
            o0[row * 512 + nn] = f2bf(sgv * bf2f(e0[row * 512 + nn]));  // Z*S
          } else if (g == 1) {
            o1[row * 512 + nn] = f2bf(1.0f - sgv);  // 1-G
          } else {
            o2[row * 512 + nn] = f2bf(sgv * bf2f(e0[row * 512 + nn]));  // S*R
          }
        } else {
          const float h = tanhf(v);
          const float omg = bf2f(e0[row * 512 + col]);
          const float zs = bf2f(e1[row * 512 + col]);
          o0[row * 512 + col] = f2bf(omg * h + zs);  // S_new
        }
      }
    }
  }
}

}  // namespace

extern "C" void kernel_launch(void* const* d_in, const int* in_sizes, int n_in,
                              void* d_out, int out_size, void* d_ws, size_t ws_size,
                              hipStream_t stream) {
  const float* X = (const float*)d_in[0];
  const float* t = (const float*)d_in[1];
  const float* W_in = (const float*)d_in[2];
  const float* b_in = (const float*)d_in[3];
  const float* W_h1 = (const float*)d_in[4];
  const float* b_h1 = (const float*)d_in[5];
  const float* W_hd = (const float*)d_in[6];
  const float* b_hd = (const float*)d_in[7];
  const float* dgm_W = (const float*)d_in[8];
  const float* dgm_b = (const float*)d_in[9];
  const float* W_out = (const float*)d_in[10];
  const float* b_out = (const float*)d_in[11];
  float* out = (float*)d_out;
  char* ws = (char*)d_ws;

  size_t off = 0;
  auto alloc = [&](size_t bytes) {
    size_t o = off;
    off = (off + bytes + 255) & ~(size_t)255;
    return o;
  };
  size_t o_wth1 = alloc((size_t)512 * 512 * 2);
  size_t o_wthd = alloc((size_t)512 * 512 * 2);
  size_t o_wtzgr = alloc((size_t)3 * 1536 * 1024 * 2);
  size_t o_wth = alloc((size_t)3 * 512 * 1024 * 2);
  size_t o_bzgr = alloc((size_t)3 * 1536 * 4);
  size_t o_bh = alloc((size_t)3 * 512 * 4);
  size_t actoff = off;

  unsigned short* wth1 = (unsigned short*)(ws + o_wth1);
  unsigned short* wthd = (unsigned short*)(ws + o_wthd);
  unsigned short* wtzgr = (unsigned short*)(ws + o_wtzgr);
  unsigned short* wth = (unsigned short*)(ws + o_wth);
  float* bzgr = (float*)(ws + o_bzgr);
  float* bh = (float*)(ws + o_bh);

  size_t avail = ws_size > actoff ? ws_size - actoff : 0;
  int nch = 1;
  while (nch < 256 && (size_t)(B_ROWS / nch) * 512 * 2 * 5 > avail) nch <<= 1;
  const int R = B_ROWS / nch;
  unsigned short* xb = (unsigned short*)(ws + actoff);
  unsigned short* Sb = xb + (size_t)R * 512;
  unsigned short* ZSb = Sb + (size_t)R * 512;
  unsigned short* OGb = ZSb + (size_t)R * 512;
  unsigned short* SRb = OGb + (size_t)R * 512;

  pack_t_k<<<1024, 256, 0, stream>>>(W_h1, wth1);
  pack_t_k<<<1024, 256, 0, stream>>>(W_hd, wthd);
  pack_zgr_k<<<18432, 256, 0, stream>>>(dgm_W, wtzgr);
  pack_h_k<<<6144, 256, 0, stream>>>(dgm_W, wth);
  pack_bias_k<<<24, 256, 0, stream>>>(dgm_b, bzgr, bh);

  const int MT = R / 128;
  for (int c = 0; c < nch; ++c) {
    long row0 = (long)c * R;
    dim3 g8(8, MT), g24(24, MT);
    // x0 = tanh(inp@W_in + b_in)  -> ZSb (scratch)
    front0_k<<<R * 2, 256, 0, stream>>>(X, t, W_in, b_in, ZSb, row0);
    // x1 = tanh(x0@W_h1 + b_h1)   -> OGb (scratch)
    gemmS_k<0, 8><<<g8, 256, 0, stream>>>(ZSb, ZSb, wth1, b_h1, OGb, nullptr, nullptr,
                                          nullptr, nullptr);
    // x = x1@W_hd + b_hd          -> xb and Sb
    gemmS_k<1, 8><<<g8, 256, 0, stream>>>(OGb, OGb, wthd, b_hd, xb, Sb, nullptr,
                                          nullptr, nullptr);
    for (int l = 0; l < 3; ++l) {
      // gates: [x|S] @ Wzgr -> Z*S, 1-G, S*R
      gemmS_k<2, 16><<<g24, 256, 0, stream>>>(xb, Sb, wtzgr + (size_t)l * 1536 * 1024,
                                              bzgr + l * 1536, ZSb, OGb, SRb, Sb, nullptr);
      // H + S update: [x|S*R] @ Wh ; S = (1-G)*tanh + Z*S
      gemmS_k<3, 16><<<g8, 256, 0, stream>>>(xb, SRb, wth + (size_t)l * 512 * 1024,
                                             bh + l * 512, Sb, nullptr, nullptr, OGb, ZSb);
    }
    head_k<<<R / 4, 256, 0, stream>>>(Sb, W_out, b_out, out, row0);
  }
}